// Round 1
// baseline (10940.778 us; speedup 1.0000x reference)
//
#include <hip/hip_runtime.h>

#define B_SZ 64
#define S_LEN 32
#define HID 128
#define VOC 96
#define DEPTH 500
#define NW 4                 // waves per block
#define TPB (NW * 64)
#define LPC (NW / 2)         // lanes cooperating per output column
#define CPW (HID / NW)       // columns per wave
#define KSPL (HID / LPC)     // k-range per lane
#define EPSV 1e-6f

__device__ __forceinline__ float wave_sum64(float v) {
#pragma unroll
    for (int m = 32; m; m >>= 1) v += __shfl_xor(v, m, 64);
    return v;
}

__global__ __launch_bounds__(TPB, 1) void rnn_char_lm(
    const int* __restrict__ chars, const float* __restrict__ hidden,
    const float* __restrict__ embed_w, const float* __restrict__ W_g,
    const float* __restrict__ b_g, const float* __restrict__ pre_s,
    const float* __restrict__ post_s, const float* __restrict__ rw_g,
    const float* __restrict__ rb_g, float* __restrict__ out)
{
    __shared__ float hbuf[2][HID];      // double-buffered normalized-input staging
    __shared__ float partials[2][NW];   // double-buffered per-wave sumsq partials
    __shared__ float hpost[HID];        // post-norm h for readout
    __shared__ float rwT[HID * VOC];    // readout_w transposed [k][v]

    const int b = blockIdx.x;
    const int tid = threadIdx.x;
    const int w = tid >> 6;
    const int lane = tid & 63;
    const int j = w * CPW + (lane / LPC);   // output column owned by this lane
    const int ks = lane & (LPC - 1);        // k-split index within column pair
    const int kbase = ks * KSPL;

    // one-time: stage readout_w transposed into LDS (coalesced global read)
    for (int e = tid; e < VOC * HID; e += TPB) {
        int v = e >> 7;           // e / 128
        int k = e & (HID - 1);
        rwT[k * VOC + v] = rw_g[e];
    }

    // one-time: W' = pre_scale[k] * W[k][j] into registers (fold RMSNorm scale)
    float Wreg[KSPL];
#pragma unroll
    for (int kk = 0; kk < KSPL; ++kk) {
        int k = kbase + kk;
        Wreg[kk] = pre_s[k] * W_g[k * HID + j];
    }
    const float b_val = b_g[j];
    const float ps_post = post_s[j];
    const float rb_val = (tid < VOC) ? rb_g[tid] : 0.0f;
    float h = hidden[b * HID + j];

    __syncthreads();

    int p = 0;
    for (int t = 0; t < S_LEN; ++t) {
        const int c = chars[b * S_LEN + t];
        const float eb = embed_w[c * HID + j] + b_val;

        for (int it = 0; it < DEPTH; ++it) {
            // --- pre-barrier: stage h, reduce sum(h^2) ---
            // each column duplicated LPC times across the wave -> factor folded below
            float wsum = wave_sum64(h * h);
            if (lane == 0) partials[p][w] = wsum;
            if (ks == 0) hbuf[p][j] = h;
            __syncthreads();

            // --- post-barrier: total sumsq -> rnorm (overlaps with dot below) ---
            float tot = 0.0f;
#pragma unroll
            for (int q = 0; q < NW; ++q) tot += partials[p][q];
            const float rnorm = 1.0f / sqrtf(tot * (1.0f / (LPC * (float)HID)) + EPSV);

            // --- dot: out[j] partial over this lane's k range ---
            float acc0 = 0.0f, acc1 = 0.0f;
            const float4* hb4 = reinterpret_cast<const float4*>(&hbuf[p][kbase]);
#pragma unroll
            for (int q = 0; q < KSPL / 8; ++q) {
                float4 x = hb4[2 * q];
                float4 y = hb4[2 * q + 1];
                acc0 = fmaf(x.x, Wreg[8 * q + 0], acc0);
                acc1 = fmaf(x.y, Wreg[8 * q + 1], acc1);
                acc0 = fmaf(x.z, Wreg[8 * q + 2], acc0);
                acc1 = fmaf(x.w, Wreg[8 * q + 3], acc1);
                acc0 = fmaf(y.x, Wreg[8 * q + 4], acc0);
                acc1 = fmaf(y.y, Wreg[8 * q + 5], acc1);
                acc0 = fmaf(y.z, Wreg[8 * q + 6], acc0);
                acc1 = fmaf(y.w, Wreg[8 * q + 7], acc1);
            }
            float dsum = acc0 + acc1;
#pragma unroll
            for (int m = 1; m < LPC; m <<= 1) dsum += __shfl_xor(dsum, m, 64);

            const float pre = fmaf(dsum, rnorm, eb);
            h += fmaxf(pre, 0.0f);
            p ^= 1;
        }

        // --- end of timestep: post-norm (replaces h), readout ---
        float wsum = wave_sum64(h * h);
        if (lane == 0) partials[p][w] = wsum;
        __syncthreads();
        float tot = 0.0f;
#pragma unroll
        for (int q = 0; q < NW; ++q) tot += partials[p][q];
        const float rnp = 1.0f / sqrtf(tot * (1.0f / (LPC * (float)HID)) + EPSV);
        h = h * rnp * ps_post;            // carry = post-normed h
        if (ks == 0) hpost[j] = h;
        p ^= 1;
        __syncthreads();

        if (tid < VOC) {
            float acc0 = 0.0f, acc1 = 0.0f;
            const float4* hp4 = reinterpret_cast<const float4*>(hpost);
#pragma unroll
            for (int k4 = 0; k4 < HID / 4; ++k4) {
                float4 x = hp4[k4];
                acc0 = fmaf(x.x, rwT[(4 * k4 + 0) * VOC + tid], acc0);
                acc1 = fmaf(x.y, rwT[(4 * k4 + 1) * VOC + tid], acc1);
                acc0 = fmaf(x.z, rwT[(4 * k4 + 2) * VOC + tid], acc0);
                acc1 = fmaf(x.w, rwT[(4 * k4 + 3) * VOC + tid], acc1);
            }
            out[(b * S_LEN + t) * VOC + tid] = acc0 + acc1 + rb_val;
        }
        // no barrier needed here: next hpost write is 500 barriers away,
        // and iteration writes touch disjoint LDS arrays.
    }

    if (ks == 0) out[B_SZ * S_LEN * VOC + b * HID + j] = h;
}

extern "C" void kernel_launch(void* const* d_in, const int* in_sizes, int n_in,
                              void* d_out, int out_size, void* d_ws, size_t ws_size,
                              hipStream_t stream)
{
    const int* chars      = (const int*)d_in[0];
    const float* hidden   = (const float*)d_in[1];
    const float* embed_w  = (const float*)d_in[2];
    const float* W_g      = (const float*)d_in[3];
    const float* b_g      = (const float*)d_in[4];
    const float* pre_s    = (const float*)d_in[5];
    const float* post_s   = (const float*)d_in[6];
    const float* rw_g     = (const float*)d_in[7];
    const float* rb_g     = (const float*)d_in[8];
    float* out            = (float*)d_out;

    rnn_char_lm<<<dim3(B_SZ), dim3(TPB), 0, stream>>>(
        chars, hidden, embed_w, W_g, b_g, pre_s, post_s, rw_g, rb_g, out);
}

// Round 2
// 5883.503 us; speedup vs baseline: 1.8596x; 1.8596x over previous
//
#include <hip/hip_runtime.h>

#define B_SZ 64
#define S_LEN 32
#define HID 128
#define VOC 96
#define DEPTH 500
#define NW 4                 // waves per block
#define TPB (NW * 64)
#define EPSV 1e-6f

typedef __attribute__((ext_vector_type(2))) float f32x2;

// swap adjacent lanes (xor 1) via DPP quad_perm [1,0,3,2] — VALU latency, no LDS
__device__ __forceinline__ float dpp_xor1(float v) {
    return __int_as_float(__builtin_amdgcn_update_dpp(
        0, __float_as_int(v), 0xB1, 0xF, 0xF, true));
}

__device__ __forceinline__ float fast_rsqrt(float x) {
    float r;
    asm("v_rsq_f32 %0, %1" : "=v"(r) : "v"(x));
    return r;
}

__device__ __forceinline__ float wave_sum64(float v) {
#pragma unroll
    for (int m = 32; m; m >>= 1) v += __shfl_xor(v, m, 64);
    return v;
}

#if defined(__has_builtin)
#if __has_builtin(__builtin_elementwise_fma)
#define VFMA(a, b, c) __builtin_elementwise_fma((a), (b), (c))
#endif
#endif
#ifndef VFMA
__device__ __forceinline__ f32x2 vfma_(f32x2 a, f32x2 b, f32x2 c) {
    f32x2 r; r.x = fmaf(a.x, b.x, c.x); r.y = fmaf(a.y, b.y, c.y); return r;
}
#define VFMA(a, b, c) vfma_((a), (b), (c))
#endif

__global__ __launch_bounds__(TPB, 1) void rnn_char_lm(
    const int* __restrict__ chars, const float* __restrict__ hidden,
    const float* __restrict__ embed_w, const float* __restrict__ W_g,
    const float* __restrict__ b_g, const float* __restrict__ pre_s,
    const float* __restrict__ post_s, const float* __restrict__ rw_g,
    const float* __restrict__ rb_g, float* __restrict__ out)
{
    __shared__ __align__(16) float hbuf[2][HID];  // double-buffered h staging
    __shared__ float partials[NW];                // per-wave sumsq (epilogue only)
    __shared__ __align__(16) float hpost[HID];    // post-norm h for readout
    __shared__ float rwT[HID * VOC];              // readout_w transposed [k][v]

    const int b = blockIdx.x;
    const int tid = threadIdx.x;
    const int w = tid >> 6;
    const int lane = tid & 63;
    const int j = (w << 5) + (lane >> 1);   // output column owned by this lane
    const int ks = lane & 1;                // k-split half (0: k<64, 1: k>=64)
    const int kbase = ks << 6;

    // one-time: stage readout_w transposed into LDS (coalesced global read)
    for (int e = tid; e < VOC * HID; e += TPB) {
        int v = e >> 7;
        int k = e & (HID - 1);
        rwT[k * VOC + v] = rw_g[e];
    }

    // one-time: W' = pre_scale[k] * W[k][j], packed as float2 over k
    f32x2 W2[32];
#pragma unroll
    for (int q = 0; q < 32; ++q) {
        int k0 = kbase + 2 * q;
        f32x2 t;
        t.x = pre_s[k0] * W_g[k0 * HID + j];
        t.y = pre_s[k0 + 1] * W_g[(k0 + 1) * HID + j];
        W2[q] = t;
    }
    const float b_val = b_g[j];
    const float ps_post = post_s[j];
    const float rb_val = (tid < VOC) ? rb_g[tid] : 0.0f;
    float h = hidden[b * HID + j];

    __syncthreads();

// one recurrent iteration with compile-time buffer parity P.
// dot and sumsq fused over the same LDS reads; lane-pair combine via DPP.
#define ITER(P)                                                            \
    {                                                                      \
        if (ks == 0) hbuf[P][j] = h;                                       \
        __syncthreads();                                                   \
        const float4* hb4 = (const float4*)(&hbuf[P][kbase]);              \
        f32x2 d0 = {0.f, 0.f}, d1 = {0.f, 0.f};                            \
        f32x2 s0 = {0.f, 0.f}, s1 = {0.f, 0.f};                            \
        _Pragma("unroll")                                                  \
        for (int q = 0; q < 16; ++q) {                                     \
            float4 x4 = hb4[q];                                            \
            f32x2 lo, hi;                                                  \
            lo.x = x4.x; lo.y = x4.y; hi.x = x4.z; hi.y = x4.w;            \
            d0 = VFMA(lo, W2[2 * q], d0);                                  \
            s0 = VFMA(lo, lo, s0);                                         \
            d1 = VFMA(hi, W2[2 * q + 1], d1);                              \
            s1 = VFMA(hi, hi, s1);                                         \
        }                                                                  \
        d0 = d0 + d1;                                                      \
        s0 = s0 + s1;                                                      \
        float dsum = d0.x + d0.y;                                          \
        float ss = s0.x + s0.y;                                            \
        dsum += dpp_xor1(dsum);                                            \
        ss += dpp_xor1(ss);                                                \
        float rnorm = fast_rsqrt(fmaf(ss, 1.0f / HID, EPSV));              \
        h += fmaxf(fmaf(dsum, rnorm, eb), 0.0f);                           \
    }

    for (int t = 0; t < S_LEN; ++t) {
        const int c = chars[b * S_LEN + t];
        const float eb = embed_w[c * HID + j] + b_val;

        for (int it = 0; it < DEPTH / 2; ++it) {
            ITER(0)
            ITER(1)
        }

        // --- end of timestep: post-norm (replaces h), readout ---
        float wsum = wave_sum64(h * h);        // wave covers 32 cols x2 copies
        if (lane == 0) partials[w] = wsum;
        __syncthreads();
        float tot = partials[0] + partials[1] + partials[2] + partials[3];
        float rnp = 1.0f / sqrtf(tot * (1.0f / (2 * HID)) + EPSV);
        h = h * rnp * ps_post;                 // carry = post-normed h
        if (ks == 0) hpost[j] = h;
        __syncthreads();

        if (tid < VOC) {
            float acc0 = 0.0f, acc1 = 0.0f;
            const float4* hp4 = reinterpret_cast<const float4*>(hpost);
#pragma unroll
            for (int k4 = 0; k4 < HID / 4; ++k4) {
                float4 x = hp4[k4];
                acc0 = fmaf(x.x, rwT[(4 * k4 + 0) * VOC + tid], acc0);
                acc1 = fmaf(x.y, rwT[(4 * k4 + 1) * VOC + tid], acc1);
                acc0 = fmaf(x.z, rwT[(4 * k4 + 2) * VOC + tid], acc0);
                acc1 = fmaf(x.w, rwT[(4 * k4 + 3) * VOC + tid], acc1);
            }
            out[(b * S_LEN + t) * VOC + tid] = acc0 + acc1 + rb_val;
        }
        // next timestep's first write (hbuf[0]) is a disjoint LDS array and is
        // followed by a barrier, so no extra barrier needed here.
    }

    if (ks == 0) out[B_SZ * S_LEN * VOC + b * HID + j] = h;
}

extern "C" void kernel_launch(void* const* d_in, const int* in_sizes, int n_in,
                              void* d_out, int out_size, void* d_ws, size_t ws_size,
                              hipStream_t stream)
{
    const int* chars      = (const int*)d_in[0];
    const float* hidden   = (const float*)d_in[1];
    const float* embed_w  = (const float*)d_in[2];
    const float* W_g      = (const float*)d_in[3];
    const float* b_g      = (const float*)d_in[4];
    const float* pre_s    = (const float*)d_in[5];
    const float* post_s   = (const float*)d_in[6];
    const float* rw_g     = (const float*)d_in[7];
    const float* rb_g     = (const float*)d_in[8];
    float* out            = (float*)d_out;

    rnn_char_lm<<<dim3(B_SZ), dim3(TPB), 0, stream>>>(
        chars, hidden, embed_w, W_g, b_g, pre_s, post_s, rw_g, rb_g, out);
}